// Round 9
// baseline (160.369 us; speedup 1.0000x reference)
//
#include <hip/hip_runtime.h>

#define GBLOCK 256
#define BLOCK 128
#define IR 4
#define JCHUNK 64
#define IPB (BLOCK * IR)          // 512 i-rows per block
#define QF (IPB / JCHUNK)         // 8 j-chunks per i-band

// exp(-d2/s^2) = exp2(d2*K), K = -1/(s^2*ln2); K2 = 16*K1 exactly
#define LN2 0.69314718055994530942
#define K1F ((float)(-1.0 / (0.08 * 0.08 * LN2)))
#define W2F 0.0625f  // (0.02/0.08)^2

// ws layout:
//   float4 ws4[4F]:  A_mesh0[F], A_mesh1[F], B_mesh0[F], B_mesh1[F]
//     A = (g*Cx, g*Cy, g*Cz, K1*|C|^2)  g = sqrt(-2*K1)
//     B = (Mx, My, Mz, 0)               M = N / sqrt(L)  (areas folded in)
//   float partials[geomSlots + pairBlocks]  at ws4 + 4F
//   unsigned counter  right after partials
// 2 dispatches total: geom (also zeroes counter), pair (last block sums
// all partials and writes out[0] -- no memset, no final_reduce kernel).

__global__ void geom_kernel(const float* __restrict__ vpred,
                            const float* __restrict__ vtarg,
                            const int* __restrict__ pf,
                            const int* __restrict__ tf,
                            float4* __restrict__ ws4,
                            float* __restrict__ partials,
                            unsigned* __restrict__ counter, int F)
{
    if (blockIdx.x == 0 && threadIdx.x == 0) *counter = 0u;  // read only by next dispatch

    int id = blockIdx.x * blockDim.x + threadIdx.x;
    float diag = 0.0f;
    if (id < 2 * F) {
        int m = (id >= F) ? 1 : 0;
        int f = id - m * F;
        const float* Vv = m ? vtarg : vpred;
        const int* Fc = m ? tf : pf;
        int i0 = Fc[3 * f + 0];
        int i1 = Fc[3 * f + 1];
        int i2 = Fc[3 * f + 2];
        float ax = Vv[3 * i0 + 0], ay = Vv[3 * i0 + 1], az = Vv[3 * i0 + 2];
        float bx = Vv[3 * i1 + 0], by = Vv[3 * i1 + 1], bz = Vv[3 * i1 + 2];
        float cx = Vv[3 * i2 + 0], cy = Vv[3 * i2 + 1], cz = Vv[3 * i2 + 2];

        const float third = 1.0f / 3.0f;
        float Cx = (ax + bx + cx) * third;
        float Cy = (ay + by + cy) * third;
        float Cz = (az + bz + cz) * third;

        float e1x = bx - ax, e1y = by - ay, e1z = bz - az;
        float e2x = cx - ax, e2y = cy - ay, e2z = cz - az;
        float Nx = 0.5f * (e1y * e2z - e1z * e2y);
        float Ny = 0.5f * (e1z * e2x - e1x * e2z);
        float Nz = 0.5f * (e1x * e2y - e1y * e2x);
        float nn = Nx * Nx + Ny * Ny + Nz * Nz;
        float L = sqrtf(nn + 1e-12f);
        float invSL = 1.0f / sqrtf(L);

        const float g = sqrtf(-2.0f * K1F);
        float c2 = Cx * Cx + Cy * Cy + Cz * Cz;
        ws4[m * F + f] = make_float4(g * Cx, g * Cy, g * Cz, K1F * c2);
        ws4[2 * F + m * F + f] =
            make_float4(Nx * invSL, Ny * invSL, Nz * invSL, 0.0f);

        // analytic diagonal of both symmetric terms: (1+W2)*(|N|^2/L)^2
        float d = nn / L;
        diag = (1.0f + W2F) * d * d;
    }
    for (int off = 32; off > 0; off >>= 1) diag += __shfl_down(diag, off, 64);
    int wid = threadIdx.x >> 6;
    if ((threadIdx.x & 63) == 0)
        partials[blockIdx.x * (GBLOCK / 64) + wid] = diag;  // plain store
}

// j-loop with register prefetch; e2 = exp2(16*tt) = ((e1^2)^2)^2.
#define JLOOP(PRED)                                                        \
    {                                                                      \
        float4 an = sA[0], bn = sB[0];                                     \
        _Pragma("unroll 2")                                                \
        for (int j = 0; j < jn; ++j) {                                     \
            float4 a = an, b = bn;                                         \
            an = sA[j + 1];                                                \
            bn = sB[j + 1];                                                \
            _Pragma("unroll")                                              \
            for (int k = 0; k < IR; ++k) {                                 \
                float tt = s1i[k] + a.w;                                   \
                tt = fmaf(pxi[k], a.x, tt);                                \
                tt = fmaf(pyi[k], a.y, tt);                                \
                tt = fmaf(pzi[k], a.z, tt);                                \
                float nd = mxi[k] * b.x;                                   \
                nd = fmaf(myi[k], b.y, nd);                                \
                nd = fmaf(mzi[k], b.z, nd);                                \
                float p = nd * nd;                                         \
                if (PRED) p = (j0 + j < ibase + k * BLOCK) ? p : 0.0f;     \
                float e1 = __builtin_amdgcn_exp2f(tt);                     \
                float u = e1 * e1;                                         \
                float u2 = u * u;                                          \
                float e2 = u2 * u2;                                        \
                accA[k] = fmaf(p, e1, accA[k]);                            \
                accB[k] = fmaf(p, e2, accB[k]);                            \
            }                                                              \
        }                                                                  \
    }

__launch_bounds__(BLOCK, 8)
__global__ void pair_kernel(const float4* __restrict__ ws4,
                            float* __restrict__ partials,   // base incl. geom slots
                            int geomSlots, int F, int nJC, int nSym,
                            int nPairBlocks, unsigned* __restrict__ counter,
                            float* __restrict__ out)
{
    int bid = blockIdx.x;
    int t, ib, jc;
    float coeff;
    bool predFlag = false;

    if (bid < 2 * nSym) {
        t = (bid < nSym) ? 0 : 1;
        int r = bid - t * nSym;
        int ibf = 0, off = 0;
        for (;;) {
            int c = QF * (ibf + 1);
            if (c > nJC) c = nJC;
            if (r < off + c) break;
            off += c;
            ibf++;
        }
        ib = ibf;
        jc = r - off;
        coeff = 2.0f;
        predFlag = (jc >= ib * QF);  // diagonal-crossing chunk
    } else {
        int r = bid - 2 * nSym;
        t = 2;
        ib = r / nJC;
        jc = r - ib * nJC;
        coeff = -2.0f;
    }

    int X = (t == 1) ? 1 : 0;
    int Y = (t == 0) ? 0 : 1;
    const float4* __restrict__ A_x = ws4 + X * F;
    const float4* __restrict__ B_x = ws4 + 2 * F + X * F;
    const float4* __restrict__ A_y = ws4 + Y * F;
    const float4* __restrict__ B_y = ws4 + 2 * F + Y * F;

    __shared__ float4 sA[JCHUNK + 1];  // +1: prefetch overreads one slot
    __shared__ float4 sB[JCHUNK + 1];

    int tid = threadIdx.x;
    int j0 = jc * JCHUNK;
    int jn = (F - j0 < JCHUNK) ? (F - j0) : JCHUNK;
    if (tid < JCHUNK) {
        if (tid < jn) sA[tid] = A_y[j0 + tid];
    } else {
        int s = tid - JCHUNK;
        if (s < jn) sB[s] = B_y[j0 + s];
    }
    __syncthreads();

    float pxi[IR], pyi[IR], pzi[IR], s1i[IR];
    float mxi[IR], myi[IR], mzi[IR];
    float accA[IR], accB[IR];
    int ibase = ib * IPB + tid;
#pragma unroll
    for (int k = 0; k < IR; k++) {
        int i = ibase + k * BLOCK;
        float4 a = make_float4(0.f, 0.f, 0.f, 0.f);
        float4 b = make_float4(0.f, 0.f, 0.f, 0.f);
        if (i < F) { a = A_x[i]; b = B_x[i]; }
        pxi[k] = a.x; pyi[k] = a.y; pzi[k] = a.z; s1i[k] = a.w;
        mxi[k] = b.x; myi[k] = b.y; mzi[k] = b.z;
        accA[k] = 0.0f; accB[k] = 0.0f;
    }

    if (!predFlag) {
        JLOOP(false)
    } else {
        JLOOP(true)
    }

    float sAcc = 0.0f, sBcc = 0.0f;
#pragma unroll
    for (int k = 0; k < IR; k++) { sAcc += accA[k]; sBcc += accB[k]; }
    float ps = (sAcc + W2F * sBcc) * coeff;

    // wave reduce -> LDS -> one plain store per block
    for (int off = 32; off > 0; off >>= 1) ps += __shfl_down(ps, off, 64);
    __shared__ float wsum[BLOCK / 64];
    if ((tid & 63) == 0) wsum[tid >> 6] = ps;
    __syncthreads();

    __shared__ bool amLast;
    if (tid == 0) {
        partials[geomSlots + bid] = wsum[0] + wsum[1];
        __threadfence();                         // release partial
        unsigned done = atomicAdd(counter, 1u);  // device-scope, 1/block
        amLast = (done == (unsigned)(nPairBlocks - 1));
    }
    __syncthreads();

    if (amLast) {
        __threadfence();  // acquire all partials
        int nTot = geomSlots + nPairBlocks;
        float s = 0.0f;
        for (int i = tid; i < nTot; i += BLOCK) s += partials[i];
        for (int off = 32; off > 0; off >>= 1) s += __shfl_down(s, off, 64);
        __shared__ float fsum[BLOCK / 64];
        if ((tid & 63) == 0) fsum[tid >> 6] = s;
        __syncthreads();
        if (tid == 0) out[0] = fsum[0] + fsum[1];
    }
}

extern "C" void kernel_launch(void* const* d_in, const int* in_sizes, int n_in,
                              void* d_out, int out_size, void* d_ws, size_t ws_size,
                              hipStream_t stream) {
    const float* vpred = (const float*)d_in[0];
    const float* vtarg = (const float*)d_in[1];
    const int* pf = (const int*)d_in[2];
    const int* tf = (const int*)d_in[3];
    float* out = (float*)d_out;
    float4* ws4 = (float4*)d_ws;

    int F = in_sizes[2] / 3;  // B == 1

    int gblocks = (2 * F + GBLOCK - 1) / GBLOCK;
    int geomSlots = gblocks * (GBLOCK / 64);

    int nIB = (F + IPB - 1) / IPB;
    int nJC = (F + JCHUNK - 1) / JCHUNK;
    int nSym = 0;
    for (int ib = 0; ib < nIB; ++ib) {
        int c = QF * (ib + 1);
        if (c > nJC) c = nJC;
        nSym += c;
    }
    int pairBlocks = 2 * nSym + nIB * nJC;

    float* partials = (float*)(ws4 + 4 * F);
    unsigned* counter = (unsigned*)(partials + geomSlots + pairBlocks);

    geom_kernel<<<gblocks, GBLOCK, 0, stream>>>(
        vpred, vtarg, pf, tf, ws4, partials, counter, F);

    pair_kernel<<<pairBlocks, BLOCK, 0, stream>>>(
        ws4, partials, geomSlots, F, nJC, nSym, pairBlocks, counter, out);
}

// Round 10
// 120.377 us; speedup vs baseline: 1.3322x; 1.3322x over previous
//
#include <hip/hip_runtime.h>

#define GBLOCK 256
#define BLOCK 256
#define IR 8
#define JCHUNK 64
#define IPB (BLOCK * IR)          // 2048 i-rows per block
#define QF (IPB / JCHUNK)         // 32 j-chunks per i-band

// exp(-d2/s^2) = exp2(d2*K), K = -1/(s^2*ln2); K2 = 16*K1 exactly
#define LN2 0.69314718055994530942
#define K1F ((float)(-1.0 / (0.08 * 0.08 * LN2)))
#define W2F 0.0625f  // (0.02/0.08)^2

// ws layout:
//   float4 ws4[4F]:  A_mesh0[F], A_mesh1[F], B_mesh0[F], B_mesh1[F]
//     A = (g*Cx, g*Cy, g*Cz, K1*|C|^2)  g = sqrt(-2*K1)
//     B = (Mx, My, Mz, 0)               M = N / sqrt(L)  (areas folded in)
//   float partials[geomSlots + pairBlocks]  at ws4 + 4F
// NO global atomics anywhere (R6/R9 lesson: same-address atomics serialize
// at ~15ns each and become the kernel floor). Plain stores + tiny reduce.

__global__ void geom_kernel(const float* __restrict__ vpred,
                            const float* __restrict__ vtarg,
                            const int* __restrict__ pf,
                            const int* __restrict__ tf,
                            float4* __restrict__ ws4,
                            float* __restrict__ partials, int F)
{
    int id = blockIdx.x * blockDim.x + threadIdx.x;
    float diag = 0.0f;
    if (id < 2 * F) {
        int m = (id >= F) ? 1 : 0;
        int f = id - m * F;
        const float* Vv = m ? vtarg : vpred;
        const int* Fc = m ? tf : pf;
        int i0 = Fc[3 * f + 0];
        int i1 = Fc[3 * f + 1];
        int i2 = Fc[3 * f + 2];
        float ax = Vv[3 * i0 + 0], ay = Vv[3 * i0 + 1], az = Vv[3 * i0 + 2];
        float bx = Vv[3 * i1 + 0], by = Vv[3 * i1 + 1], bz = Vv[3 * i1 + 2];
        float cx = Vv[3 * i2 + 0], cy = Vv[3 * i2 + 1], cz = Vv[3 * i2 + 2];

        const float third = 1.0f / 3.0f;
        float Cx = (ax + bx + cx) * third;
        float Cy = (ay + by + cy) * third;
        float Cz = (az + bz + cz) * third;

        float e1x = bx - ax, e1y = by - ay, e1z = bz - az;
        float e2x = cx - ax, e2y = cy - ay, e2z = cz - az;
        float Nx = 0.5f * (e1y * e2z - e1z * e2y);
        float Ny = 0.5f * (e1z * e2x - e1x * e2z);
        float Nz = 0.5f * (e1x * e2y - e1y * e2x);
        float nn = Nx * Nx + Ny * Ny + Nz * Nz;
        float L = sqrtf(nn + 1e-12f);
        float invSL = 1.0f / sqrtf(L);

        const float g = sqrtf(-2.0f * K1F);
        float c2 = Cx * Cx + Cy * Cy + Cz * Cz;
        ws4[m * F + f] = make_float4(g * Cx, g * Cy, g * Cz, K1F * c2);
        ws4[2 * F + m * F + f] =
            make_float4(Nx * invSL, Ny * invSL, Nz * invSL, 0.0f);

        // analytic diagonal of both symmetric terms: (1+W2)*(|N|^2/L)^2
        float d = nn / L;
        diag = (1.0f + W2F) * d * d;
    }
    for (int off = 32; off > 0; off >>= 1) diag += __shfl_down(diag, off, 64);
    int wid = threadIdx.x >> 6;
    if ((threadIdx.x & 63) == 0)
        partials[blockIdx.x * (GBLOCK / 64) + wid] = diag;  // plain store
}

// j-loop with register prefetch; e2 = exp2(16*tt) = ((e1^2)^2)^2.
#define JLOOP(PRED)                                                        \
    {                                                                      \
        float4 an = sA[0], bn = sB[0];                                     \
        for (int j = 0; j < jn; ++j) {                                     \
            float4 a = an, b = bn;                                         \
            an = sA[j + 1];                                                \
            bn = sB[j + 1];                                                \
            _Pragma("unroll")                                              \
            for (int k = 0; k < IR; ++k) {                                 \
                float tt = s1i[k] + a.w;                                   \
                tt = fmaf(pxi[k], a.x, tt);                                \
                tt = fmaf(pyi[k], a.y, tt);                                \
                tt = fmaf(pzi[k], a.z, tt);                                \
                float nd = mxi[k] * b.x;                                   \
                nd = fmaf(myi[k], b.y, nd);                                \
                nd = fmaf(mzi[k], b.z, nd);                                \
                float p = nd * nd;                                         \
                if (PRED) p = (j0 + j < ibase + k * BLOCK) ? p : 0.0f;     \
                float e1 = __builtin_amdgcn_exp2f(tt);                     \
                float u = e1 * e1;                                         \
                float u2 = u * u;                                          \
                float e2 = u2 * u2;                                        \
                accA[k] = fmaf(p, e1, accA[k]);                            \
                accB[k] = fmaf(p, e2, accB[k]);                            \
            }                                                              \
        }                                                                  \
    }

__launch_bounds__(BLOCK, 4)
__global__ void pair_kernel(const float4* __restrict__ ws4,
                            float* __restrict__ partials, int F,
                            int nJC, int nSym)
{
    int bid = blockIdx.x;
    int t, ib, jc;
    float coeff;
    bool predFlag = false;

    if (bid < 2 * nSym) {
        t = (bid < nSym) ? 0 : 1;
        int r = bid - t * nSym;
        int ibf = 0, off = 0;
        for (;;) {
            int c = QF * (ibf + 1);
            if (c > nJC) c = nJC;
            if (r < off + c) break;
            off += c;
            ibf++;
        }
        ib = ibf;
        jc = r - off;
        coeff = 2.0f;
        predFlag = (jc >= ib * QF);  // diagonal-crossing chunk
    } else {
        int r = bid - 2 * nSym;
        t = 2;
        ib = r / nJC;
        jc = r - ib * nJC;
        coeff = -2.0f;
    }

    int X = (t == 1) ? 1 : 0;
    int Y = (t == 0) ? 0 : 1;
    const float4* __restrict__ A_x = ws4 + X * F;
    const float4* __restrict__ B_x = ws4 + 2 * F + X * F;
    const float4* __restrict__ A_y = ws4 + Y * F;
    const float4* __restrict__ B_y = ws4 + 2 * F + Y * F;

    __shared__ float4 sA[JCHUNK + 1];  // +1: prefetch overreads one slot
    __shared__ float4 sB[JCHUNK + 1];

    int tid = threadIdx.x;
    int j0 = jc * JCHUNK;
    int jn = (F - j0 < JCHUNK) ? (F - j0) : JCHUNK;
    if (tid < JCHUNK) {
        if (tid < jn) sA[tid] = A_y[j0 + tid];
    } else if (tid < 2 * JCHUNK) {
        int s = tid - JCHUNK;
        if (s < jn) sB[s] = B_y[j0 + s];
    }
    __syncthreads();

    float pxi[IR], pyi[IR], pzi[IR], s1i[IR];
    float mxi[IR], myi[IR], mzi[IR];
    float accA[IR], accB[IR];
    int ibase = ib * IPB + tid;
#pragma unroll
    for (int k = 0; k < IR; k++) {
        int i = ibase + k * BLOCK;
        float4 a = make_float4(0.f, 0.f, 0.f, 0.f);
        float4 b = make_float4(0.f, 0.f, 0.f, 0.f);
        if (i < F) { a = A_x[i]; b = B_x[i]; }
        pxi[k] = a.x; pyi[k] = a.y; pzi[k] = a.z; s1i[k] = a.w;
        mxi[k] = b.x; myi[k] = b.y; mzi[k] = b.z;
        accA[k] = 0.0f; accB[k] = 0.0f;
    }

    if (!predFlag) {
        JLOOP(false)
    } else {
        JLOOP(true)
    }

    float sAcc = 0.0f, sBcc = 0.0f;
#pragma unroll
    for (int k = 0; k < IR; k++) { sAcc += accA[k]; sBcc += accB[k]; }
    float ps = (sAcc + W2F * sBcc) * coeff;

    // wave reduce -> LDS -> one plain store per block (NO atomics)
    for (int off = 32; off > 0; off >>= 1) ps += __shfl_down(ps, off, 64);
    __shared__ float wsum[BLOCK / 64];
    int wid = tid >> 6;
    if ((tid & 63) == 0) wsum[wid] = ps;
    __syncthreads();
    if (tid == 0) {
        partials[bid] = wsum[0] + wsum[1] + wsum[2] + wsum[3];
    }
}

__global__ void final_reduce(const float* __restrict__ partials, int n,
                             float* __restrict__ out)
{
    float s = 0.0f;
    for (int i = threadIdx.x; i < n; i += GBLOCK) s += partials[i];
    for (int off = 32; off > 0; off >>= 1) s += __shfl_down(s, off, 64);
    __shared__ float wsum[GBLOCK / 64];
    int wid = threadIdx.x >> 6;
    if ((threadIdx.x & 63) == 0) wsum[wid] = s;
    __syncthreads();
    if (threadIdx.x == 0)
        out[0] = wsum[0] + wsum[1] + wsum[2] + wsum[3];
}

extern "C" void kernel_launch(void* const* d_in, const int* in_sizes, int n_in,
                              void* d_out, int out_size, void* d_ws, size_t ws_size,
                              hipStream_t stream) {
    const float* vpred = (const float*)d_in[0];
    const float* vtarg = (const float*)d_in[1];
    const int* pf = (const int*)d_in[2];
    const int* tf = (const int*)d_in[3];
    float* out = (float*)d_out;
    float4* ws4 = (float4*)d_ws;

    int F = in_sizes[2] / 3;  // B == 1

    // partials live after the 4F float4 geometry region
    float* partials = (float*)(ws4 + 4 * F);

    int gblocks = (2 * F + GBLOCK - 1) / GBLOCK;
    int geomSlots = gblocks * (GBLOCK / 64);

    int nIB = (F + IPB - 1) / IPB;
    int nJC = (F + JCHUNK - 1) / JCHUNK;
    int nSym = 0;
    for (int ib = 0; ib < nIB; ++ib) {
        int c = QF * (ib + 1);
        if (c > nJC) c = nJC;
        nSym += c;
    }
    int pairBlocks = 2 * nSym + nIB * nJC;

    geom_kernel<<<gblocks, GBLOCK, 0, stream>>>(
        vpred, vtarg, pf, tf, ws4, partials, F);

    pair_kernel<<<pairBlocks, BLOCK, 0, stream>>>(
        ws4, partials + geomSlots, F, nJC, nSym);

    final_reduce<<<1, GBLOCK, 0, stream>>>(
        partials, geomSlots + pairBlocks, out);
}

// Round 11
// 112.118 us; speedup vs baseline: 1.4304x; 1.0737x over previous
//
#include <hip/hip_runtime.h>

#define GBLOCK 256
#define BLOCK 256
#define IR 2
#define JCHUNK 32
#define IPB (BLOCK * IR)     // 512 i-rows per tile
#define QF (IPB / JCHUNK)    // 16 j-chunks per i-band
#define NBLK 2048            // fixed grid: 8 blocks/CU on 256 CUs

// exp(-d2/s^2) = exp2(d2*K), K = -1/(s^2*ln2); K2 = 16*K1 exactly
#define LN2 0.69314718055994530942
#define K1F ((float)(-1.0 / (0.08 * 0.08 * LN2)))
#define W2F 0.0625f  // (0.02/0.08)^2

typedef const __attribute__((address_space(1))) void* gas1_t;
typedef __attribute__((address_space(3))) void* las3_t;

// ws layout:
//   float4 ws4[4F]:  A_mesh0[F], A_mesh1[F], B_mesh0[F], B_mesh1[F]
//     A = (g*Cx, g*Cy, g*Cz, K1*|C|^2)  g = sqrt(-2*K1)
//     B = (Mx, My, Mz, 0)               M = N / sqrt(L)  (areas folded in)
//   float partials[geomSlots + NBLK] at ws4 + 4F
// NO global atomics (R6/R9: same-address atomics serialize ~15ns each).

__global__ void geom_kernel(const float* __restrict__ vpred,
                            const float* __restrict__ vtarg,
                            const int* __restrict__ pf,
                            const int* __restrict__ tf,
                            float4* __restrict__ ws4,
                            float* __restrict__ partials, int F)
{
    int id = blockIdx.x * blockDim.x + threadIdx.x;
    float diag = 0.0f;
    if (id < 2 * F) {
        int m = (id >= F) ? 1 : 0;
        int f = id - m * F;
        const float* Vv = m ? vtarg : vpred;
        const int* Fc = m ? tf : pf;
        int i0 = Fc[3 * f + 0];
        int i1 = Fc[3 * f + 1];
        int i2 = Fc[3 * f + 2];
        float ax = Vv[3 * i0 + 0], ay = Vv[3 * i0 + 1], az = Vv[3 * i0 + 2];
        float bx = Vv[3 * i1 + 0], by = Vv[3 * i1 + 1], bz = Vv[3 * i1 + 2];
        float cx = Vv[3 * i2 + 0], cy = Vv[3 * i2 + 1], cz = Vv[3 * i2 + 2];

        const float third = 1.0f / 3.0f;
        float Cx = (ax + bx + cx) * third;
        float Cy = (ay + by + cy) * third;
        float Cz = (az + bz + cz) * third;

        float e1x = bx - ax, e1y = by - ay, e1z = bz - az;
        float e2x = cx - ax, e2y = cy - ay, e2z = cz - az;
        float Nx = 0.5f * (e1y * e2z - e1z * e2y);
        float Ny = 0.5f * (e1z * e2x - e1x * e2z);
        float Nz = 0.5f * (e1x * e2y - e1y * e2x);
        float nn = Nx * Nx + Ny * Ny + Nz * Nz;
        float L = sqrtf(nn + 1e-12f);
        float invSL = 1.0f / sqrtf(L);

        const float g = sqrtf(-2.0f * K1F);
        float c2 = Cx * Cx + Cy * Cy + Cz * Cz;
        ws4[m * F + f] = make_float4(g * Cx, g * Cy, g * Cz, K1F * c2);
        ws4[2 * F + m * F + f] =
            make_float4(Nx * invSL, Ny * invSL, Nz * invSL, 0.0f);

        float d = nn / L;                       // diagonal: (1+W2)*(|N|^2/L)^2
        diag = (1.0f + W2F) * d * d;
    }
    for (int off = 32; off > 0; off >>= 1) diag += __shfl_down(diag, off, 64);
    int wid = threadIdx.x >> 6;
    if ((threadIdx.x & 63) == 0)
        partials[blockIdx.x * (GBLOCK / 64) + wid] = diag;  // plain store
}

__device__ __forceinline__ void decode_tile(int idx, int nSym, int nJC,
                                            int* t, int* ib, int* jc, bool* pred)
{
    if (idx < 2 * nSym) {
        int tt = (idx < nSym) ? 0 : 1;
        int r = idx - tt * nSym;
        int off = 0, ibf = 0;
        for (;;) {
            int c = QF * (ibf + 1);
            if (c > nJC) c = nJC;
            if (r < off + c) break;
            off += c;
            ibf++;
        }
        *t = tt; *ib = ibf; *jc = r - off;
        *pred = ((r - off) >= ibf * QF);   // diagonal-crossing chunk
    } else {
        int r = idx - 2 * nSym;
        *t = 2; *ib = r / nJC; *jc = r - (*ib) * nJC;
        *pred = false;
    }
}

// wave 0 stages one j-chunk: lanes 0..31 -> A_y[j0+lane], 32..63 -> B_y[...].
// One global_load_lds: LDS dest = base + lane*16 (linear), so LDS holds
// [A(32 float4) | B(32 float4)] contiguously.
__device__ __forceinline__ void stage_chunk(const float4* __restrict__ ws4,
                                            int F, int t, int jc,
                                            float4* dstBase, int lane)
{
    int Y = (t == 0) ? 0 : 1;
    int j0 = jc * JCHUNK;
    const float4* src = (lane < JCHUNK)
        ? (ws4 + Y * F + j0 + lane)
        : (ws4 + 2 * F + Y * F + j0 + (lane - JCHUNK));
    __builtin_amdgcn_global_load_lds((gas1_t)src, (las3_t)dstBase, 16, 0, 0);
}

#define JLOOP(PRED)                                                        \
    {                                                                      \
        float4 an = sA[0], bn = sB[0];                                     \
        _Pragma("unroll 2")                                                \
        for (int j = 0; j < jn; ++j) {                                     \
            float4 a = an, b = bn;                                         \
            an = sA[j + 1];                                                \
            bn = sB[j + 1];                                                \
            _Pragma("unroll")                                              \
            for (int k = 0; k < IR; ++k) {                                 \
                float tt2 = s1i[k] + a.w;                                  \
                tt2 = fmaf(pxi[k], a.x, tt2);                              \
                tt2 = fmaf(pyi[k], a.y, tt2);                              \
                tt2 = fmaf(pzi[k], a.z, tt2);                              \
                float nd = mxi[k] * b.x;                                   \
                nd = fmaf(myi[k], b.y, nd);                                \
                nd = fmaf(mzi[k], b.z, nd);                                \
                float p = nd * nd;                                         \
                if (PRED) p = (j0 + j < ibase + k * BLOCK) ? p : 0.0f;     \
                float e1 = __builtin_amdgcn_exp2f(tt2);                    \
                float u = e1 * e1;                                         \
                float u2 = u * u;                                          \
                float e2 = u2 * u2;                                        \
                accA[k] = fmaf(p, e1, accA[k]);                            \
                accB[k] = fmaf(p, e2, accB[k]);                            \
            }                                                              \
        }                                                                  \
    }

__launch_bounds__(BLOCK, 8)
__global__ void pair_kernel(const float4* __restrict__ ws4,
                            float* __restrict__ partials, int F,
                            int nJC, int nSym, int nT)
{
    __shared__ float4 sbuf[2][2 * JCHUNK];

    int bid = blockIdx.x;
    int tid = threadIdx.x;

    // balanced contiguous tile range for this block
    int q = nT / NBLK, rr = nT - q * NBLK;
    int start = bid * q + (bid < rr ? bid : rr);
    int end = start + q + (bid < rr ? 1 : 0);

    int t, ib, jc; bool pred;
    decode_tile(start, nSym, nJC, &t, &ib, &jc, &pred);

    if (tid < 64) stage_chunk(ws4, F, t, jc, &sbuf[0][0], tid);
    __syncthreads();  // compiler drains wave0's vmcnt before barrier

    float tot = 0.0f;
    int cur = 0;
    int prevKey = -1;
    float pxi[IR], pyi[IR], pzi[IR], s1i[IR];
    float mxi[IR], myi[IR], mzi[IR];

    for (int ti = start; ti < end; ++ti) {
        // prefetch next tile's j-chunk into alternate buffer (async)
        int tn_t = t, tn_ib = ib, tn_jc = jc; bool tn_pred = pred;
        if (ti + 1 < end) {
            decode_tile(ti + 1, nSym, nJC, &tn_t, &tn_ib, &tn_jc, &tn_pred);
            if (tid < 64) stage_chunk(ws4, F, tn_t, tn_jc, &sbuf[cur ^ 1][0], tid);
        }

        // i-fragments (reload only when (term, i-band) changes)
        int X = (t == 1) ? 1 : 0;
        int key = t * 64 + ib;
        int ibase = ib * IPB + tid;
        if (key != prevKey) {
            prevKey = key;
            const float4* __restrict__ A_x = ws4 + X * F;
            const float4* __restrict__ B_x = ws4 + 2 * F + X * F;
#pragma unroll
            for (int k = 0; k < IR; ++k) {
                int i = ibase + k * BLOCK;
                float4 a = make_float4(0.f, 0.f, 0.f, 0.f);
                float4 b = make_float4(0.f, 0.f, 0.f, 0.f);
                if (i < F) { a = A_x[i]; b = B_x[i]; }
                pxi[k] = a.x; pyi[k] = a.y; pzi[k] = a.z; s1i[k] = a.w;
                mxi[k] = b.x; myi[k] = b.y; mzi[k] = b.z;
            }
        }

        const float4* sA = &sbuf[cur][0];
        const float4* sB = &sbuf[cur][JCHUNK];
        int j0 = jc * JCHUNK;
        int jn = (F - j0 < JCHUNK) ? (F - j0) : JCHUNK;

        float accA[IR], accB[IR];
#pragma unroll
        for (int k = 0; k < IR; ++k) { accA[k] = 0.0f; accB[k] = 0.0f; }

        if (!pred) {
            JLOOP(false)
        } else {
            JLOOP(true)
        }

        float sAcc = 0.0f, sBcc = 0.0f;
#pragma unroll
        for (int k = 0; k < IR; ++k) { sAcc += accA[k]; sBcc += accB[k]; }
        float coeff = (t == 2) ? -2.0f : 2.0f;
        tot = fmaf(coeff, fmaf(W2F, sBcc, sAcc), tot);

        __syncthreads();  // next chunk staged; current buffer free
        cur ^= 1;
        t = tn_t; ib = tn_ib; jc = tn_jc; pred = tn_pred;
    }

    // block reduce -> one plain store (NO atomics)
    for (int off = 32; off > 0; off >>= 1) tot += __shfl_down(tot, off, 64);
    __shared__ float wsum[BLOCK / 64];
    if ((tid & 63) == 0) wsum[tid >> 6] = tot;
    __syncthreads();
    if (tid == 0)
        partials[bid] = wsum[0] + wsum[1] + wsum[2] + wsum[3];
}

__global__ void final_reduce(const float* __restrict__ partials, int n,
                             float* __restrict__ out)
{
    float s = 0.0f;
    for (int i = threadIdx.x; i < n; i += GBLOCK) s += partials[i];
    for (int off = 32; off > 0; off >>= 1) s += __shfl_down(s, off, 64);
    __shared__ float wsum[GBLOCK / 64];
    int wid = threadIdx.x >> 6;
    if ((threadIdx.x & 63) == 0) wsum[wid] = s;
    __syncthreads();
    if (threadIdx.x == 0)
        out[0] = wsum[0] + wsum[1] + wsum[2] + wsum[3];
}

extern "C" void kernel_launch(void* const* d_in, const int* in_sizes, int n_in,
                              void* d_out, int out_size, void* d_ws, size_t ws_size,
                              hipStream_t stream) {
    const float* vpred = (const float*)d_in[0];
    const float* vtarg = (const float*)d_in[1];
    const int* pf = (const int*)d_in[2];
    const int* tf = (const int*)d_in[3];
    float* out = (float*)d_out;
    float4* ws4 = (float4*)d_ws;

    int F = in_sizes[2] / 3;  // B == 1

    float* partials = (float*)(ws4 + 4 * F);

    int gblocks = (2 * F + GBLOCK - 1) / GBLOCK;
    int geomSlots = gblocks * (GBLOCK / 64);

    int nIB = (F + IPB - 1) / IPB;
    int nJC = (F + JCHUNK - 1) / JCHUNK;
    int nSym = 0;
    for (int ib = 0; ib < nIB; ++ib) {
        int c = QF * (ib + 1);
        if (c > nJC) c = nJC;
        nSym += c;
    }
    int nT = 2 * nSym + nIB * nJC;

    geom_kernel<<<gblocks, GBLOCK, 0, stream>>>(
        vpred, vtarg, pf, tf, ws4, partials, F);

    pair_kernel<<<NBLK, BLOCK, 0, stream>>>(
        ws4, partials + geomSlots, F, nJC, nSym, nT);

    final_reduce<<<1, GBLOCK, 0, stream>>>(
        partials, geomSlots + NBLK, out);
}